// Round 4
// baseline (566.321 us; speedup 1.0000x reference)
//
#include <hip/hip_runtime.h>
#include <stdint.h>

#define B 32
#define P 24564
#define NCLS 21
#define NOBJ 24
#define THRESH 0.5f
#define GRID 512
#define BPB 16        // blocks per batch
#define ITERS 6       // 96 chunks of 256 priors / BPB
#define NBKT 2048     // histogram buckets: float bits >> 20
#define LCAP 5376     // LDS boundary-list capacity

// ws layout (bytes), total 3,412,672
#define OFF_ACC     0        // double[4]: loc_sum, conf_pos, conf_neg
#define OFF_BAR     32       // unsigned: grid barrier counter
#define OFF_NPOS    64       // int[B]
#define OFF_OBJBEST 192      // ull[B*NOBJ] = 6144
#define INIT_BYTES  6336
#define OFF_HIST    6336     // u32[B*NBKT] = 262144
#define OFF_CENEG   268480   // float[B*P] = 3144192

__device__ __forceinline__ unsigned long long umax64(unsigned long long a, unsigned long long b) {
    return a > b ? a : b;
}

// Device-scope grid barrier: all GRID blocks are co-resident by construction
// (launch_bounds(256,2) -> 2 blocks/CU * 256 CU = 512 = GRID; LDS 30.6KB allows 5/CU).
__device__ __forceinline__ void gridbar(unsigned* cnt) {
    __threadfence();
    __syncthreads();
    if (threadIdx.x == 0) {
        unsigned my = __hip_atomic_fetch_add(cnt, 1u, __ATOMIC_ACQ_REL, __HIP_MEMORY_SCOPE_AGENT);
        unsigned target = (my / GRID + 1u) * GRID;
        long spins = 0;
        while (__hip_atomic_load(cnt, __ATOMIC_ACQUIRE, __HIP_MEMORY_SCOPE_AGENT) < target) {
            __builtin_amdgcn_s_sleep(8);
            if (++spins > 2000000L) break;   // bounded: wrong-answer beats hang
        }
    }
    __syncthreads();
    __threadfence();
}

__global__ __launch_bounds__(256, 2) void k_all(
    const float* __restrict__ pred_cls, const float* __restrict__ pred_loc,
    const float* __restrict__ gt_boxes, const int* __restrict__ gt_labels,
    const float* __restrict__ anchor, char* __restrict__ ws, float* __restrict__ out) {
#pragma clang fp contract(off)
    double* acc = (double*)(ws + OFF_ACC);
    unsigned* bar = (unsigned*)(ws + OFF_BAR);
    int* n_pos = (int*)(ws + OFF_NPOS);
    unsigned long long* obj_best = (unsigned long long*)(ws + OFF_OBJBEST);
    unsigned* hist = (unsigned*)(ws + OFF_HIST);
    float* ce_neg = (float*)(ws + OFF_CENEG);

    __shared__ float4 sbox[NOBJ];
    __shared__ int slab[NOBJ];
    __shared__ int sobj[NOBJ];
    __shared__ unsigned long long sbest[NOBJ];
    __shared__ __align__(16) float sx[256 * NCLS];   // 21504 B; reused in select phase
    __shared__ unsigned shist[NBKT];                 // 8192 B
    __shared__ float swf[8];
    __shared__ int swi[4];
    __shared__ double swd[4];
    __shared__ int sscal[4];                         // b0, Kp, lcnt, cgt

    const int tid = threadIdx.x;
    const int b = blockIdx.x / BPB;
    const int j = blockIdx.x % BPB;

    // ---------- Phase A: per-object best prior (force-match argmax) + zero hist slice ----------
    {
        if (tid < NOBJ) {
            const float* g = gt_boxes + (size_t)(b * NOBJ + tid) * 4;
            sbox[tid] = make_float4(g[0], g[1], g[2], g[3]);
            sbest[tid] = 0ull;
        }
        if (tid < NBKT / BPB) hist[b * NBKT + j * (NBKT / BPB) + tid] = 0u;  // 128 words/block
        __syncthreads();
        unsigned long long best[NOBJ];
#pragma unroll
        for (int n = 0; n < NOBJ; n++) best[n] = 0ull;
        int pend = min(P, (j + 1) * 1536);
        for (int p = j * 1536 + tid; p < pend; p += 256) {
            float4 a = *(const float4*)(anchor + (size_t)p * 4);
            float ax0 = a.x - a.z * 0.5f, ay0 = a.y - a.w * 0.5f;
            float ax1 = a.x + a.z * 0.5f, ay1 = a.y + a.w * 0.5f;
            float area_a = (ax1 - ax0) * (ay1 - ay0);
            unsigned pk = ~(unsigned)p;
#pragma unroll
            for (int n = 0; n < NOBJ; n++) {
                float4 bx = sbox[n];
                float ltx = fmaxf(bx.x, ax0), lty = fmaxf(bx.y, ay0);
                float rbx = fminf(bx.z, ax1), rby = fminf(bx.w, ay1);
                float w = fmaxf(rbx - ltx, 0.f), h = fmaxf(rby - lty, 0.f);
                float inter = w * h;
                float area_o = (bx.z - bx.x) * (bx.w - bx.y);
                float iou = inter / (area_o + area_a - inter);
                unsigned long long key = ((unsigned long long)__float_as_uint(iou) << 32) | pk;
                best[n] = umax64(best[n], key);
            }
        }
#pragma unroll
        for (int n = 0; n < NOBJ; n++) {
            unsigned long long v = best[n];
            for (int off = 32; off > 0; off >>= 1) v = umax64(v, __shfl_down(v, off, 64));
            if ((tid & 63) == 0) atomicMax(&sbest[n], v);
        }
        __syncthreads();
        if (tid < NOBJ) atomicMax(&obj_best[b * NOBJ + tid], sbest[tid]);
    }
    gridbar(bar);

    // ---------- Phase B: fused match + loc-L1 + CE + histogram (double-buffered) ----------
    {
        if (tid < NOBJ) {
            slab[tid] = gt_labels[b * NOBJ + tid];
            sobj[tid] = (int)(~(unsigned)(obj_best[b * NOBJ + tid] & 0xFFFFFFFFull));
        }
        for (int i = tid; i < NBKT; i += 256) shist[i] = 0u;
        __syncthreads();

        float lsum = 0.f, cpos = 0.f;
        int lnp = 0;
        float4 nxt[6];
        {   // prologue prefetch: chunk j (always full, j < 16)
            const float4* g4 = (const float4*)(pred_cls + ((size_t)b * P + j * 256) * NCLS);
#pragma unroll
            for (int k = 0; k < 6; k++) { int idx = tid + k * 256; if (idx < 1344) nxt[k] = g4[idx]; }
        }
        for (int it = 0; it < ITERS; it++) {
            int c = j + it * BPB;
            int p0 = c * 256;
            int nelem = min(256, P - p0);
            int nf4 = (nelem * NCLS) >> 2;   // nelem*21 divisible by 4 for 256 and 244
#pragma unroll
            for (int k = 0; k < 6; k++) { int idx = tid + k * 256; if (idx < nf4) ((float4*)sx)[idx] = nxt[k]; }
            __syncthreads();
            if (it < ITERS - 1) {  // prefetch next chunk (overlaps compute below)
                int pn0 = (c + BPB) * 256;
                int nf4n = (min(256, P - pn0) * NCLS) >> 2;
                const float4* g4 = (const float4*)(pred_cls + ((size_t)b * P + pn0) * NCLS);
#pragma unroll
                for (int k = 0; k < 6; k++) { int idx = tid + k * 256; if (idx < nf4n) nxt[k] = g4[idx]; }
            }
            if (tid < nelem) {
                int p = p0 + tid;
                float4 a = *(const float4*)(anchor + (size_t)p * 4);
                float ax0 = a.x - a.z * 0.5f, ay0 = a.y - a.w * 0.5f;
                float ax1 = a.x + a.z * 0.5f, ay1 = a.y + a.w * 0.5f;
                float area_a = (ax1 - ax0) * (ay1 - ay0);
                float bv = -1.f;
                int bn = 0;
#pragma unroll
                for (int n = 0; n < NOBJ; n++) {
                    float4 bx = sbox[n];
                    float ltx = fmaxf(bx.x, ax0), lty = fmaxf(bx.y, ay0);
                    float rbx = fminf(bx.z, ax1), rby = fminf(bx.w, ay1);
                    float w = fmaxf(rbx - ltx, 0.f), h = fmaxf(rby - lty, 0.f);
                    float inter = w * h;
                    float area_o = (bx.z - bx.x) * (bx.w - bx.y);
                    float iou = inter / (area_o + area_a - inter);
                    if (p == sobj[n]) iou = 1.0f;
                    if (iou > bv) { bv = iou; bn = n; }
                }
                int pos = (bv >= THRESH) ? 1 : 0;
                int cls = pos ? (slab[bn] + 1) : 0;
                const float* x = sx + tid * NCLS;
                float m = x[0];
#pragma unroll
                for (int q = 1; q < NCLS; q++) m = fmaxf(m, x[q]);
                float s = 0.f;
#pragma unroll
                for (int q = 0; q < NCLS; q++) s += __expf(x[q] - m);
                float ce = m + __logf(s) - x[cls];
                size_t idx = (size_t)b * P + p;
                if (pos) {
                    lnp++;
                    cpos += ce;
                    ce_neg[idx] = 0.f;
                    float4 bx = sbox[bn];
                    float bcx = (bx.x + bx.z) * 0.5f, bcy = (bx.y + bx.w) * 0.5f;
                    float bw = bx.z - bx.x, bh = bx.w - bx.y;
                    float t0 = (bcx - a.x) / (a.z / 10.0f);
                    float t1 = (bcy - a.y) / (a.w / 10.0f);
                    float t2 = __logf(bw / a.z) * 5.0f;
                    float t3 = __logf(bh / a.w) * 5.0f;
                    float4 pl = *(const float4*)(pred_loc + idx * 4);
                    lsum += fabsf(pl.x - t0) + fabsf(pl.y - t1) + fabsf(pl.z - t2) + fabsf(pl.w - t3);
                } else {
                    ce_neg[idx] = ce;
                    unsigned bk = __float_as_uint(ce) >> 20;
                    atomicAdd(&shist[bk > 2047u ? 2047u : bk], 1u);
                }
            }
            __syncthreads();
        }
        for (int off = 32; off > 0; off >>= 1) {
            lsum += __shfl_down(lsum, off, 64);
            cpos += __shfl_down(cpos, off, 64);
            lnp  += __shfl_down(lnp, off, 64);
        }
        if ((tid & 63) == 0) { swf[tid >> 6] = lsum; swf[4 + (tid >> 6)] = cpos; swi[tid >> 6] = lnp; }
        __syncthreads();
        if (tid == 0) {
            float ls = swf[0] + swf[1] + swf[2] + swf[3];
            float cs = swf[4] + swf[5] + swf[6] + swf[7];
            int np = swi[0] + swi[1] + swi[2] + swi[3];
            if (np) atomicAdd(&n_pos[b], np);
            atomicAdd(&acc[0], (double)ls);
            atomicAdd(&acc[1], (double)cs);
        }
        for (int i = tid; i < NBKT; i += 256) {
            unsigned cgl = shist[i];
            if (cgl) atomicAdd(&hist[b * NBKT + i], cgl);
        }
    }
    gridbar(bar);

    // ---------- Phase C+D: per-batch boundary + hard-negative top-K sum ----------
    if (blockIdx.x < B) {
        int bb = blockIdx.x;
        int K = n_pos[bb] * 3;
        if (K > P) K = P;
        if (K > 0) {
            unsigned* part = (unsigned*)sx;          // 256
            unsigned* w64 = ((unsigned*)sx) + 256;   // 64
            for (int i = tid; i < NBKT; i += 256) shist[i] = hist[bb * NBKT + i];
            __syncthreads();
            unsigned ps = 0;
#pragma unroll
            for (int q = 0; q < 8; q++) ps += shist[tid * 8 + q];
            part[tid] = ps;
            __syncthreads();
            if (tid < 64) w64[tid] = part[tid * 4] + part[tid * 4 + 1] + part[tid * 4 + 2] + part[tid * 4 + 3];
            __syncthreads();
            if (tid == 0) {
                unsigned c = 0;
                int g = 63;
                for (; g >= 0; g--) { if (c + w64[g] >= (unsigned)K) break; c += w64[g]; }
                int b0, Kp;
                if (g < 0) {
                    b0 = 0;
                    Kp = K - (int)(c - shist[0]);
                } else {
                    int i = g * 4 + 3;
                    for (;; i--) { if (c + part[i] >= (unsigned)K) break; c += part[i]; }
                    int q = i * 8 + 7;
                    for (;; q--) { if (c + shist[q] >= (unsigned)K) break; c += shist[q]; }
                    b0 = q; Kp = K - (int)c;
                }
                sscal[0] = b0; sscal[1] = Kp; sscal[2] = 0;
            }
            __syncthreads();
            int b0 = sscal[0], Kp = sscal[1];
            unsigned* list = (unsigned*)sx;          // reuse (done with part/w64)
            const uint4* x4 = (const uint4*)(ce_neg + (size_t)bb * P);
            double s = 0.0;
            for (int i = tid; i < P / 4; i += 256) {
                uint4 v = x4[i];
                unsigned vv[4] = {v.x, v.y, v.z, v.w};
#pragma unroll
                for (int r = 0; r < 4; r++) {
                    int bk = (int)(vv[r] >> 20);
                    if (bk > b0) {
                        s += (double)__uint_as_float(vv[r]);
                    } else if (bk == b0) {
                        int pos = atomicAdd(&sscal[2], 1);
                        if (pos < LCAP) list[pos] = vv[r];
                    }
                }
            }
            __syncthreads();
            int lcnt = sscal[2];
            bool useList = (lcnt <= LCAP);
            const unsigned* src = useList ? list : (const unsigned*)(ce_neg + (size_t)bb * P);
            int n = useList ? lcnt : P;
            unsigned T = (unsigned)b0 << 20;          // all candidates share the top 11 bits
            if (Kp > 0) {
                for (int bit = 19; bit >= 0; bit--) {
                    unsigned cand = T | (1u << bit);
                    int cc = 0;
                    for (int i = tid; i < n; i += 256) {
                        unsigned v = src[i];
                        if (!useList && (int)(v >> 20) != b0) continue;
                        cc += (v >= cand) ? 1 : 0;
                    }
                    for (int off = 32; off > 0; off >>= 1) cc += __shfl_down(cc, off, 64);
                    if ((tid & 63) == 0) swi[tid >> 6] = cc;
                    __syncthreads();
                    int tot = swi[0] + swi[1] + swi[2] + swi[3];
                    __syncthreads();
                    if (tot >= Kp) T = cand;
                }
                int cgt = 0;
                for (int i = tid; i < n; i += 256) {
                    unsigned v = src[i];
                    if (!useList && (int)(v >> 20) != b0) continue;
                    if (v > T) { cgt++; s += (double)__uint_as_float(v); }
                }
                for (int off = 32; off > 0; off >>= 1) cgt += __shfl_down(cgt, off, 64);
                if ((tid & 63) == 0) swi[tid >> 6] = cgt;
                __syncthreads();
                if (tid == 0) sscal[3] = swi[0] + swi[1] + swi[2] + swi[3];
                __syncthreads();
            }
            for (int off = 32; off > 0; off >>= 1) s += __shfl_down(s, off, 64);
            if ((tid & 63) == 0) swd[tid >> 6] = s;
            __syncthreads();
            if (tid == 0) {
                double tot = swd[0] + swd[1] + swd[2] + swd[3];
                if (Kp > 0) tot += (double)(Kp - sscal[3]) * (double)__uint_as_float(T);
                atomicAdd(&acc[2], tot);
            }
        }
    }
    gridbar(bar);

    // ---------- Phase E: final scalars ----------
    if (blockIdx.x == 0 && tid == 0) {
        int npt = 0;
        for (int bb = 0; bb < B; bb++) npt += n_pos[bb];
        double npf = (double)npt;
        float conf = (float)((acc[1] + acc[2]) / npf);
        float loc = 10.0f * (float)(acc[0] / (npf * 4.0));
        out[0] = conf + loc;
        out[1] = conf;
        out[2] = loc;
    }
}

extern "C" void kernel_launch(void* const* d_in, const int* in_sizes, int n_in,
                              void* d_out, int out_size, void* d_ws, size_t ws_size,
                              hipStream_t stream) {
    const float* pred_cls = (const float*)d_in[0];
    const float* pred_loc = (const float*)d_in[1];
    const float* gt_boxes = (const float*)d_in[2];
    const int*   gt_labels = (const int*)d_in[3];
    const float* anchor   = (const float*)d_in[4];
    float* out = (float*)d_out;
    char* ws = (char*)d_ws;

    hipMemsetAsync(ws, 0, INIT_BYTES, stream);
    k_all<<<GRID, 256, 0, stream>>>(pred_cls, pred_loc, gt_boxes, gt_labels, anchor, ws, out);
}

// Round 5
// 202.899 us; speedup vs baseline: 2.7911x; 2.7911x over previous
//
#include <hip/hip_runtime.h>
#include <stdint.h>

#define B 32
#define P 24564      // divisible by 4
#define NCLS 21
#define NOBJ 24
#define THRESH 0.5f
#define NBKT 2048    // histogram buckets: float bits >> 20
#define LCAP 5376    // LDS boundary-list capacity (k_sel)

// ws layout (bytes)
#define OFF_ACC     0        // double[3]: loc_sum, conf_pos, conf_neg
#define OFF_ARRV    32       // unsigned: k_sel arrival counter
#define OFF_NPOS    64       // int[B]
#define OFF_OBJBEST 192      // ull[B*NOBJ] = 6144
#define INIT_BYTES  6336     // memset range (acc, arrv, n_pos, obj_best)
#define OFF_HIST    6336     // u32[B*NBKT] = 262144 (zeroed in k_objmax)
#define OFF_CENEG   268480   // float[B*P] = 3144192

__device__ __forceinline__ unsigned long long umax64(unsigned long long a, unsigned long long b) {
    return a > b ? a : b;
}

// ---------------- Kernel 1: per-object best prior (force-match argmax) + hist zero -----------
__global__ __launch_bounds__(256) void k_objmax(
    const float* __restrict__ gt_boxes, const float* __restrict__ anchor,
    unsigned long long* __restrict__ obj_best, unsigned* __restrict__ hist) {
#pragma clang fp contract(off)
    int b = blockIdx.y;
    int j = blockIdx.x;                       // 0..15
    int tid = threadIdx.x;
    // zero the histogram for later dispatches (512 blocks x 128 words = 65536)
    if (tid < 128) hist[(blockIdx.y * 16 + blockIdx.x) * 128 + tid] = 0u;
    __shared__ float4 sbox[NOBJ];
    __shared__ unsigned long long sbest[NOBJ];
    if (tid < NOBJ) {
        const float* g = gt_boxes + (size_t)(b * NOBJ + tid) * 4;
        sbox[tid] = make_float4(g[0], g[1], g[2], g[3]);
        sbest[tid] = 0ull;
    }
    __syncthreads();
    unsigned long long best[NOBJ];
#pragma unroll
    for (int n = 0; n < NOBJ; n++) best[n] = 0ull;
    int pend = min(P, (j + 1) * 1536);
    for (int p = j * 1536 + tid; p < pend; p += 256) {
        float4 a = *(const float4*)(anchor + (size_t)p * 4);
        float ax0 = a.x - a.z * 0.5f, ay0 = a.y - a.w * 0.5f;
        float ax1 = a.x + a.z * 0.5f, ay1 = a.y + a.w * 0.5f;
        float area_a = (ax1 - ax0) * (ay1 - ay0);
        unsigned pk = ~(unsigned)p;
#pragma unroll
        for (int n = 0; n < NOBJ; n++) {
            float4 bx = sbox[n];
            float ltx = fmaxf(bx.x, ax0), lty = fmaxf(bx.y, ay0);
            float rbx = fminf(bx.z, ax1), rby = fminf(bx.w, ay1);
            float w = fmaxf(rbx - ltx, 0.f), h = fmaxf(rby - lty, 0.f);
            float inter = w * h;
            float area_o = (bx.z - bx.x) * (bx.w - bx.y);
            float iou = inter / (area_o + area_a - inter);
            unsigned long long key = ((unsigned long long)__float_as_uint(iou) << 32) | pk;
            best[n] = umax64(best[n], key);
        }
    }
#pragma unroll
    for (int n = 0; n < NOBJ; n++) {
        unsigned long long v = best[n];
        for (int off = 32; off > 0; off >>= 1) v = umax64(v, __shfl_down(v, off, 64));
        if ((tid & 63) == 0) atomicMax(&sbest[n], v);
    }
    __syncthreads();
    if (tid < NOBJ) atomicMax(&obj_best[b * NOBJ + tid], sbest[tid]);
}

// ---------------- Kernel 2: fused match + loc-L1 + CE + histogram (register streaming) -------
// 768 blocks = 24 per batch; each thread owns 4 consecutive priors (21 aligned float4 loads).
__global__ __launch_bounds__(256, 2) void k_mainB(
    const float* __restrict__ pred_cls, const float* __restrict__ pred_loc,
    const float* __restrict__ gt_boxes, const int* __restrict__ gt_labels,
    const float* __restrict__ anchor, const unsigned long long* __restrict__ obj_best,
    float* __restrict__ ce_neg, unsigned* __restrict__ hist,
    int* __restrict__ n_pos, double* __restrict__ acc) {
#pragma clang fp contract(off)
    __shared__ float4 sbox[NOBJ];
    __shared__ int slab[NOBJ];
    __shared__ int sobj[NOBJ];
    __shared__ unsigned shist[NBKT];
    __shared__ float swf[8];
    __shared__ int swi[4];
    const int tid = threadIdx.x;
    const int b = blockIdx.x / 24;
    const int j = blockIdx.x % 24;

    for (int i = tid; i < NBKT; i += 256) shist[i] = 0u;
    if (tid < NOBJ) {
        const float* g = gt_boxes + (size_t)(b * NOBJ + tid) * 4;
        sbox[tid] = make_float4(g[0], g[1], g[2], g[3]);
        slab[tid] = gt_labels[b * NOBJ + tid];
        sobj[tid] = (int)(~(unsigned)(obj_best[b * NOBJ + tid] & 0xFFFFFFFFull));
    }
    __syncthreads();

    int p0 = j * 1024 + tid * 4;
    float lsum = 0.f, cpos = 0.f;
    int lnp = 0;
    if (p0 < P) {
        // 21 aligned float4 loads = 336 contiguous bytes = 4 priors x 21 classes
        float4 xx[21];
        const float4* xp = (const float4*)(pred_cls + ((size_t)b * P + p0) * NCLS);
#pragma unroll
        for (int k = 0; k < 21; k++) xx[k] = xp[k];
        const float* arr = (const float*)xx;
        float4 anc4[4];
#pragma unroll
        for (int r = 0; r < 4; r++) anc4[r] = ((const float4*)anchor)[p0 + r];
        float4 cev;
        float* cevp = (float*)&cev;
#pragma unroll
        for (int r = 0; r < 4; r++) {
            int p = p0 + r;
            float4 a = anc4[r];
            float ax0 = a.x - a.z * 0.5f, ay0 = a.y - a.w * 0.5f;
            float ax1 = a.x + a.z * 0.5f, ay1 = a.y + a.w * 0.5f;
            float area_a = (ax1 - ax0) * (ay1 - ay0);
            float bv = -1.f;
            int bn = 0;
#pragma unroll
            for (int n = 0; n < NOBJ; n++) {
                float4 bx = sbox[n];
                float ltx = fmaxf(bx.x, ax0), lty = fmaxf(bx.y, ay0);
                float rbx = fminf(bx.z, ax1), rby = fminf(bx.w, ay1);
                float w = fmaxf(rbx - ltx, 0.f), h = fmaxf(rby - lty, 0.f);
                float inter = w * h;
                float area_o = (bx.z - bx.x) * (bx.w - bx.y);
                float iou = inter / (area_o + area_a - inter);
                if (p == sobj[n]) iou = 1.0f;
                if (iou > bv) { bv = iou; bn = n; }
            }
            int pos = (bv >= THRESH) ? 1 : 0;
            int cls = pos ? (slab[bn] + 1) : 0;
            const float* x = arr + r * 21;
            float m = x[0];
#pragma unroll
            for (int q = 1; q < NCLS; q++) m = fmaxf(m, x[q]);
            float s = 0.f;
#pragma unroll
            for (int q = 0; q < NCLS; q++) s += __expf(x[q] - m);
            float xc = x[0];
#pragma unroll
            for (int q = 1; q < NCLS; q++) xc = (cls == q) ? x[q] : xc;
            float ce = m + __logf(s) - xc;
            if (pos) {
                lnp++;
                cpos += ce;
                cevp[r] = 0.f;
                float4 bx = sbox[bn];
                float bcx = (bx.x + bx.z) * 0.5f, bcy = (bx.y + bx.w) * 0.5f;
                float bw = bx.z - bx.x, bh = bx.w - bx.y;
                float t0 = (bcx - a.x) / (a.z / 10.0f);
                float t1 = (bcy - a.y) / (a.w / 10.0f);
                float t2 = __logf(bw / a.z) * 5.0f;
                float t3 = __logf(bh / a.w) * 5.0f;
                float4 pl = *(const float4*)(pred_loc + ((size_t)b * P + p) * 4);
                lsum += fabsf(pl.x - t0) + fabsf(pl.y - t1) + fabsf(pl.z - t2) + fabsf(pl.w - t3);
            } else {
                cevp[r] = ce;
                unsigned bk = __float_as_uint(ce) >> 20;
                atomicAdd(&shist[bk > 2047u ? 2047u : bk], 1u);
            }
        }
        *(float4*)(ce_neg + (size_t)b * P + p0) = cev;
    }
    for (int off = 32; off > 0; off >>= 1) {
        lsum += __shfl_down(lsum, off, 64);
        cpos += __shfl_down(cpos, off, 64);
        lnp  += __shfl_down(lnp, off, 64);
    }
    if ((tid & 63) == 0) { swf[tid >> 6] = lsum; swf[4 + (tid >> 6)] = cpos; swi[tid >> 6] = lnp; }
    __syncthreads();
    if (tid == 0) {
        float ls = swf[0] + swf[1] + swf[2] + swf[3];
        float cs = swf[4] + swf[5] + swf[6] + swf[7];
        int np = swi[0] + swi[1] + swi[2] + swi[3];
        if (np) atomicAdd(&n_pos[b], np);
        atomicAdd(&acc[0], (double)ls);
        atomicAdd(&acc[1], (double)cs);
    }
    for (int i = tid; i < NBKT; i += 256) {
        unsigned c = shist[i];
        if (c) atomicAdd(&hist[b * NBKT + i], c);
    }
}

// ---------------- Kernel 3: boundary + top-K sum + final scalars (last-arriver) --------------
__global__ __launch_bounds__(256) void k_sel(
    const float* __restrict__ ce_neg, const unsigned* __restrict__ hist,
    const int* __restrict__ n_pos, double* __restrict__ acc,
    unsigned* __restrict__ arrv, float* __restrict__ out) {
    __shared__ unsigned shist[NBKT];
    __shared__ unsigned slist[LCAP];   // head doubles as part[256]+w64[64] during boundary-find
    __shared__ int swi[4];
    __shared__ double swd[4];
    __shared__ int sscal[4];           // b0, Kp, lcnt, cgt
    const int bb = blockIdx.x;
    const int tid = threadIdx.x;
    int K = n_pos[bb] * 3;
    if (K > P) K = P;
    if (K > 0) {
        unsigned* part = slist;
        unsigned* w64 = slist + 256;
        for (int i = tid; i < NBKT; i += 256) shist[i] = hist[bb * NBKT + i];
        __syncthreads();
        unsigned ps = 0;
#pragma unroll
        for (int q = 0; q < 8; q++) ps += shist[tid * 8 + q];
        part[tid] = ps;
        __syncthreads();
        if (tid < 64) w64[tid] = part[tid * 4] + part[tid * 4 + 1] + part[tid * 4 + 2] + part[tid * 4 + 3];
        __syncthreads();
        if (tid == 0) {
            unsigned c = 0;
            int g = 63;
            for (; g >= 0; g--) { if (c + w64[g] >= (unsigned)K) break; c += w64[g]; }
            int b0, Kp;
            if (g < 0) {
                b0 = 0;
                Kp = K - (int)(c - shist[0]);
            } else {
                int i = g * 4 + 3;
                for (;; i--) { if (c + part[i] >= (unsigned)K) break; c += part[i]; }
                int q = i * 8 + 7;
                for (;; q--) { if (c + shist[q] >= (unsigned)K) break; c += shist[q]; }
                b0 = q; Kp = K - (int)c;
            }
            sscal[0] = b0; sscal[1] = Kp; sscal[2] = 0;
        }
        __syncthreads();
        int b0 = sscal[0], Kp = sscal[1];
        const uint4* x4 = (const uint4*)(ce_neg + (size_t)bb * P);
        double s = 0.0;
        for (int i = tid; i < P / 4; i += 256) {
            uint4 v = x4[i];
            unsigned vv[4] = {v.x, v.y, v.z, v.w};
#pragma unroll
            for (int r = 0; r < 4; r++) {
                int bk = (int)(vv[r] >> 20);
                if (bk > b0) {
                    s += (double)__uint_as_float(vv[r]);
                } else if (bk == b0) {
                    int pos = atomicAdd(&sscal[2], 1);
                    if (pos < LCAP) slist[pos] = vv[r];
                }
            }
        }
        __syncthreads();
        int lcnt = sscal[2];
        bool useList = (lcnt <= LCAP);
        const unsigned* src = useList ? slist : (const unsigned*)(ce_neg + (size_t)bb * P);
        int n = useList ? lcnt : P;
        unsigned T = (unsigned)b0 << 20;
        if (Kp > 0) {
            for (int bit = 19; bit >= 0; bit--) {
                unsigned cand = T | (1u << bit);
                int cc = 0;
                for (int i = tid; i < n; i += 256) {
                    unsigned v = src[i];
                    if (!useList && (int)(v >> 20) != b0) continue;
                    cc += (v >= cand) ? 1 : 0;
                }
                for (int off = 32; off > 0; off >>= 1) cc += __shfl_down(cc, off, 64);
                if ((tid & 63) == 0) swi[tid >> 6] = cc;
                __syncthreads();
                int tot = swi[0] + swi[1] + swi[2] + swi[3];
                __syncthreads();
                if (tot >= Kp) T = cand;
            }
            int cgt = 0;
            for (int i = tid; i < n; i += 256) {
                unsigned v = src[i];
                if (!useList && (int)(v >> 20) != b0) continue;
                if (v > T) { cgt++; s += (double)__uint_as_float(v); }
            }
            for (int off = 32; off > 0; off >>= 1) cgt += __shfl_down(cgt, off, 64);
            if ((tid & 63) == 0) swi[tid >> 6] = cgt;
            __syncthreads();
            if (tid == 0) sscal[3] = swi[0] + swi[1] + swi[2] + swi[3];
            __syncthreads();
        }
        for (int off = 32; off > 0; off >>= 1) s += __shfl_down(s, off, 64);
        if ((tid & 63) == 0) swd[tid >> 6] = s;
        __syncthreads();
        if (tid == 0) {
            double tot = swd[0] + swd[1] + swd[2] + swd[3];
            if (Kp > 0) tot += (double)(Kp - sscal[3]) * (double)__uint_as_float(T);
            atomicAdd(&acc[2], tot);
        }
    }
    // ---- arrival: last block computes final scalars (no spinning) ----
    __syncthreads();
    if (tid == 0) {
        __threadfence();
        unsigned done = __hip_atomic_fetch_add(arrv, 1u, __ATOMIC_ACQ_REL, __HIP_MEMORY_SCOPE_AGENT);
        if (done == B - 1) {
            int npt = 0;
            for (int k = 0; k < B; k++)
                npt += __hip_atomic_load((int*)&n_pos[k], __ATOMIC_RELAXED, __HIP_MEMORY_SCOPE_AGENT);
            unsigned long long u0 = __hip_atomic_load((unsigned long long*)&acc[0],
                                                      __ATOMIC_RELAXED, __HIP_MEMORY_SCOPE_AGENT);
            unsigned long long u1 = __hip_atomic_load((unsigned long long*)&acc[1],
                                                      __ATOMIC_RELAXED, __HIP_MEMORY_SCOPE_AGENT);
            unsigned long long u2 = __hip_atomic_load((unsigned long long*)&acc[2],
                                                      __ATOMIC_RELAXED, __HIP_MEMORY_SCOPE_AGENT);
            double a0 = __longlong_as_double((long long)u0);
            double a1 = __longlong_as_double((long long)u1);
            double a2 = __longlong_as_double((long long)u2);
            double npf = (double)npt;
            float conf = (float)((a1 + a2) / npf);
            float loc = 10.0f * (float)(a0 / (npf * 4.0));
            out[0] = conf + loc;
            out[1] = conf;
            out[2] = loc;
        }
    }
}

extern "C" void kernel_launch(void* const* d_in, const int* in_sizes, int n_in,
                              void* d_out, int out_size, void* d_ws, size_t ws_size,
                              hipStream_t stream) {
    const float* pred_cls = (const float*)d_in[0];
    const float* pred_loc = (const float*)d_in[1];
    const float* gt_boxes = (const float*)d_in[2];
    const int*   gt_labels = (const int*)d_in[3];
    const float* anchor   = (const float*)d_in[4];
    float* out = (float*)d_out;
    char* ws = (char*)d_ws;
    double* acc = (double*)(ws + OFF_ACC);
    unsigned* arrv = (unsigned*)(ws + OFF_ARRV);
    int* n_pos = (int*)(ws + OFF_NPOS);
    unsigned long long* obj_best = (unsigned long long*)(ws + OFF_OBJBEST);
    unsigned* hist = (unsigned*)(ws + OFF_HIST);
    float* ce_neg = (float*)(ws + OFF_CENEG);

    hipMemsetAsync(ws, 0, INIT_BYTES, stream);
    k_objmax<<<dim3(16, B), 256, 0, stream>>>(gt_boxes, anchor, obj_best, hist);
    k_mainB<<<24 * B, 256, 0, stream>>>(pred_cls, pred_loc, gt_boxes, gt_labels, anchor,
                                        obj_best, ce_neg, hist, n_pos, acc);
    k_sel<<<B, 256, 0, stream>>>(ce_neg, hist, n_pos, acc, arrv, out);
}